// Round 7
// baseline (304.695 us; speedup 1.0000x reference)
//
#include <hip/hip_runtime.h>

// SiLU-and-mul: x shape (4, 2048, 32768) fp32; gate = x[..., :16384],
// up = x[..., 16384:]; out = silu(gate) * up, shape (4, 2048, 16384) fp32.
// Memory-bound: 1.074 GB read + 0.537 GB write.
// R1: 316 us (5.10 TB/s) full-occupancy grid-stride.
// R3: 326 us nt+unroll4 — reverted.
// R4: 307 us (5.25 TB/s) 2 blocks/CU, block-contiguous 1MB chunks.
// R5: 295 us (5.46 TB/s) register double-buffer (8KB/wave in flight).
// R6: 293 us (5.50 TB/s) 4 blocks/CU + __expf (neutral -> not compute/latency).
// R7: burst-reorder loads: issue all 4 gate loads (4KB contiguous wave-burst)
//     then all 4 up loads, instead of g/u interleave at 1KB granularity.
//     Tests DRAM per-stream burst-length theory. If <2% -> ROOFLINE.

#define D4_HALF  4096             // float4 per half-row (16384 floats / 4)
#define D4_FULL  8192             // float4 per input row
#define BLOCK    256
#define GRID     1024             // 4 blocks/CU on 256 CUs = 16 waves/CU
#define ITER     128              // 33554432 f4 / (1024*256) exactly
#define BATCH    4                // f4 per thread per batch
#define NBATCH   (ITER / BATCH)   // 32

typedef float f4 __attribute__((ext_vector_type(4)));

__device__ __forceinline__ float silu(float x) {
    // x * sigmoid(x) = x * rcp(1 + e^-x). __expf -> v_mul+v_exp_f32;
    // v_rcp_f32 ~22.5-bit. abs err << 0.335 threshold.
    // Large -x: exp->inf, rcp->0 -> 0. Large +x: rcp(1)=1 -> x. Safe.
    return x * __builtin_amdgcn_rcpf(1.0f + __expf(-x));
}

struct Batch { f4 g[BATCH]; f4 u[BATCH]; };

__device__ __forceinline__ Batch load_batch(const f4* __restrict__ x,
                                            int base, int b) {
    Batch r;
    // Gate burst: 4 back-to-back wave loads = 4KB contiguous per wave.
#pragma unroll
    for (int k = 0; k < BATCH; ++k) {
        int i = base + (b * BATCH + k) * BLOCK;
        int gi = (i >> 12) * D4_FULL + (i & (D4_HALF - 1));
        r.g[k] = x[gi];
    }
    // Up burst: 4 back-to-back wave loads, 64KB away.
#pragma unroll
    for (int k = 0; k < BATCH; ++k) {
        int i = base + (b * BATCH + k) * BLOCK;
        int gi = (i >> 12) * D4_FULL + (i & (D4_HALF - 1));
        r.u[k] = x[gi + D4_HALF];
    }
    return r;
}

__device__ __forceinline__ void store_batch(f4* __restrict__ out,
                                            int base, int b, const Batch& t) {
#pragma unroll
    for (int k = 0; k < BATCH; ++k) {
        f4 r;
        r.x = silu(t.g[k].x) * t.u[k].x;
        r.y = silu(t.g[k].y) * t.u[k].y;
        r.z = silu(t.g[k].z) * t.u[k].z;
        r.w = silu(t.g[k].w) * t.u[k].w;
        out[base + (b * BATCH + k) * BLOCK] = r;
    }
}

__global__ void __launch_bounds__(BLOCK)
SiluAndMul_kernel(const f4* __restrict__ x, f4* __restrict__ out) {
    // Block owns a contiguous 512 KB output chunk; explicit 2-deep register
    // pipeline with static A/B names (no runtime-indexed arrays — scratch).
    int base = blockIdx.x * (BLOCK * ITER) + threadIdx.x;
    Batch A = load_batch(x, base, 0);
#pragma unroll 1
    for (int b = 0; b < NBATCH; b += 2) {
        Batch B = load_batch(x, base, b + 1);   // issue before waiting on A
        store_batch(out, base, b, A);
        if (b + 2 < NBATCH) A = load_batch(x, base, b + 2);
        store_batch(out, base, b + 1, B);
    }
}

extern "C" void kernel_launch(void* const* d_in, const int* in_sizes, int n_in,
                              void* d_out, int out_size, void* d_ws, size_t ws_size,
                              hipStream_t stream) {
    const f4* x = (const f4*)d_in[0];
    f4* out = (f4*)d_out;
    // out_size = 134217728 floats = 33554432 f4 = GRID*BLOCK*ITER exactly.
    SiluAndMul_kernel<<<GRID, BLOCK, 0, stream>>>(x, out);
}

// Round 8
// 293.020 us; speedup vs baseline: 1.0398x; 1.0398x over previous
//
#include <hip/hip_runtime.h>

// SiLU-and-mul: x shape (4, 2048, 32768) fp32; gate = x[..., :16384],
// up = x[..., 16384:]; out = silu(gate) * up, shape (4, 2048, 16384) fp32.
// Memory-bound: 1.074 GB read + 0.537 GB write.
// R1: 316 us (5.10 TB/s) full-occupancy grid-stride.
// R3: 326 us nt+unroll4 — reverted.
// R4: 307 us (5.25 TB/s) 2 blocks/CU, block-contiguous 1MB chunks.
// R5: 295 us (5.46 TB/s) register double-buffer (8KB/wave in flight).
// R6: 293 us (5.50 TB/s) 4 blocks/CU + __expf.  <- BEST
// R7: 305 us burst-reorder (same-stream 4KB bursts) — REGRESSED, reverted.
//     Interleaved g/u load order keeps both input streams' channel queues fed.
// R8: restore R6 exactly. 5.50 TB/s = 87% of 6.29 TB/s copy ceiling is the
//     structural limit for this 3-stream 2R:1W mix -> roofline.

#define D4_HALF  4096             // float4 per half-row (16384 floats / 4)
#define D4_FULL  8192             // float4 per input row
#define BLOCK    256
#define GRID     1024             // 4 blocks/CU on 256 CUs = 16 waves/CU
#define ITER     128              // 33554432 f4 / (1024*256) exactly
#define BATCH    4                // f4 per thread per batch
#define NBATCH   (ITER / BATCH)   // 32

typedef float f4 __attribute__((ext_vector_type(4)));

__device__ __forceinline__ float silu(float x) {
    // x * sigmoid(x) = x * rcp(1 + e^-x). __expf -> v_mul+v_exp_f32;
    // v_rcp_f32 ~22.5-bit. abs err << 0.335 threshold.
    // Large -x: exp->inf, rcp->0 -> 0. Large +x: rcp(1)=1 -> x. Safe.
    return x * __builtin_amdgcn_rcpf(1.0f + __expf(-x));
}

struct Batch { f4 g[BATCH]; f4 u[BATCH]; };

__device__ __forceinline__ Batch load_batch(const f4* __restrict__ x,
                                            int base, int b) {
    Batch r;
#pragma unroll
    for (int k = 0; k < BATCH; ++k) {
        int i = base + (b * BATCH + k) * BLOCK;      // output f4 index
        int gi = (i >> 12) * D4_FULL + (i & (D4_HALF - 1));
        r.g[k] = x[gi];
        r.u[k] = x[gi + D4_HALF];
    }
    return r;
}

__device__ __forceinline__ void store_batch(f4* __restrict__ out,
                                            int base, int b, const Batch& t) {
#pragma unroll
    for (int k = 0; k < BATCH; ++k) {
        f4 r;
        r.x = silu(t.g[k].x) * t.u[k].x;
        r.y = silu(t.g[k].y) * t.u[k].y;
        r.z = silu(t.g[k].z) * t.u[k].z;
        r.w = silu(t.g[k].w) * t.u[k].w;
        out[base + (b * BATCH + k) * BLOCK] = r;
    }
}

__global__ void __launch_bounds__(BLOCK)
SiluAndMul_kernel(const f4* __restrict__ x, f4* __restrict__ out) {
    // Block owns a contiguous 512 KB output chunk; explicit 2-deep register
    // pipeline with static A/B names (no runtime-indexed arrays — scratch).
    int base = blockIdx.x * (BLOCK * ITER) + threadIdx.x;
    Batch A = load_batch(x, base, 0);
#pragma unroll 1
    for (int b = 0; b < NBATCH; b += 2) {
        Batch B = load_batch(x, base, b + 1);   // issue before waiting on A
        store_batch(out, base, b, A);
        if (b + 2 < NBATCH) A = load_batch(x, base, b + 2);
        store_batch(out, base, b + 1, B);
    }
}

extern "C" void kernel_launch(void* const* d_in, const int* in_sizes, int n_in,
                              void* d_out, int out_size, void* d_ws, size_t ws_size,
                              hipStream_t stream) {
    const f4* x = (const f4*)d_in[0];
    f4* out = (f4*)d_out;
    // out_size = 134217728 floats = 33554432 f4 = GRID*BLOCK*ITER exactly.
    SiluAndMul_kernel<<<GRID, BLOCK, 0, stream>>>(x, out);
}